// Round 1
// 220.197 us; speedup vs baseline: 1.0757x; 1.0757x over previous
//
#include <hip/hip_runtime.h>
#include <math.h>

// BertBidafAttention B=16, CL=512, QL=64, H=768 — fused 4-kernel pipeline:
//   K1 k_u_beta : u = q @ W (W transposed+split in LDS), beta = q @ bias
//   K2 k_s_sm   : s = c @ u^T + beta  AND  s1 = softmax_q(s) (in-block, via LDS)
//   K3 k_sm_cols: s2t = softmax_c(s)^T -> bf16 [b][64][512]
//   K4 k_tfin   : t = (s2^T @ c) per h-slice (LDS), qT staged (LDS),
//                 out = [c, a, c*a, c*bvec],  a = s1@q, bvec = s1@t

#define B_  16
#define CL_ 512
#define QL_ 64
#define H_  768
#define M_  (B_ * CL_)   // 8192

typedef __attribute__((ext_vector_type(8))) short s8v;   // 8 bf16
typedef __attribute__((ext_vector_type(4))) float f4v;   // MFMA acc

__device__ __forceinline__ unsigned short bf16_rne(float x) {
    unsigned int u = __float_as_uint(x);
    u += 0x7fffu + ((u >> 16) & 1u);
    return (unsigned short)(u >> 16);
}
__device__ __forceinline__ float bf16_f(unsigned short h) {
    return __uint_as_float((unsigned int)h << 16);
}
__device__ __forceinline__ void split2(float x, unsigned short& h, unsigned short& l) {
    h = bf16_rne(x);
    l = bf16_rne(x - bf16_f(h));
}

// ---------- K1: u = q @ W (split-bf16; W staged+transposed+split in LDS)
//                + beta blocks (blockIdx.x >= 192) ----------
__global__ __launch_bounds__(256) void k_u_beta(const float* __restrict__ q,
    const float* __restrict__ W, const float* __restrict__ bias,
    unsigned short* __restrict__ uh, unsigned short* __restrict__ ul,
    float* __restrict__ beta)
{
    if (blockIdx.x >= 192) {
        // beta[row] = bias . q[row]
        const int row = (blockIdx.x - 192) * 4 + (threadIdx.x >> 6);
        const int lane = threadIdx.x & 63;
        float p = 0.f;
        for (int d = lane; d < H_; d += 64) p = fmaf(bias[d], q[(size_t)row * H_ + d], p);
#pragma unroll
        for (int o = 32; o; o >>= 1) p += __shfl_xor(p, o);
        if (lane == 0) beta[row] = p;
        return;
    }
    __shared__ unsigned short Wh[64][40], Wl[64][40];
    const int m0 = (blockIdx.x & 15) * 64, n0 = (blockIdx.x >> 4) * 64;
    const int t = threadIdx.x, w = t >> 6, lane = t & 63;
    const int fm = lane & 15, quad = lane >> 4;
    const int mrow = m0 + w * 16 + fm;
    const int dd = t >> 3, hc = (t & 7) * 8;
    f4v acc[4];
#pragma unroll
    for (int j = 0; j < 4; ++j) acc[j] = (f4v){0.f, 0.f, 0.f, 0.f};
    for (int k0 = 0; k0 < H_; k0 += 32) {
        // global loads first (W tile for staging, q frag for A)
        const float* wp = &W[(size_t)(k0 + dd) * H_ + n0 + hc];
        const float4 v0 = *(const float4*)wp, v1 = *(const float4*)(wp + 4);
        const float* ap = &q[(size_t)mrow * H_ + k0 + quad * 8];
        const float4 a0 = *(const float4*)ap, a1 = *(const float4*)(ap + 4);
        const float as[8] = {a0.x, a0.y, a0.z, a0.w, a1.x, a1.y, a1.z, a1.w};
        s8v fah, fal;
#pragma unroll
        for (int j = 0; j < 8; ++j) { unsigned short h, l; split2(as[j], h, l); fah[j] = (short)h; fal[j] = (short)l; }
        const float ws[8] = {v0.x, v0.y, v0.z, v0.w, v1.x, v1.y, v1.z, v1.w};
        __syncthreads();   // protect previous iteration's LDS reads
#pragma unroll
        for (int j = 0; j < 8; ++j) {
            unsigned short h, l; split2(ws[j], h, l);
            Wh[hc + j][dd] = h; Wl[hc + j][dd] = l;
        }
        __syncthreads();
#pragma unroll
        for (int tn = 0; tn < 4; ++tn) {
            const s8v bh = *(const s8v*)&Wh[tn * 16 + fm][quad * 8];
            const s8v bl = *(const s8v*)&Wl[tn * 16 + fm][quad * 8];
            acc[tn] = __builtin_amdgcn_mfma_f32_16x16x32_bf16(fah, bh, acc[tn], 0, 0, 0);
            acc[tn] = __builtin_amdgcn_mfma_f32_16x16x32_bf16(fah, bl, acc[tn], 0, 0, 0);
            acc[tn] = __builtin_amdgcn_mfma_f32_16x16x32_bf16(fal, bh, acc[tn], 0, 0, 0);
        }
    }
#pragma unroll
    for (int tn = 0; tn < 4; ++tn) {
        const int col = n0 + tn * 16 + fm;
#pragma unroll
        for (int r = 0; r < 4; ++r) {
            const int row = m0 + w * 16 + quad * 4 + r;
            unsigned short h, l; split2(acc[tn][r], h, l);
            uh[(size_t)row * H_ + col] = h;
            ul[(size_t)row * H_ + col] = l;
        }
    }
}

// ---------- K2: s = c @ u^T + beta (split-bf16) + fused row softmax -> s1 ----------
__global__ __launch_bounds__(256) void k_s_sm(const float* __restrict__ c,
    const unsigned short* __restrict__ uh, const unsigned short* __restrict__ ul,
    const float* __restrict__ beta, const int* __restrict__ q_mask,
    float* __restrict__ s, unsigned short* __restrict__ s1)
{
    __shared__ float sL[32][65];
    const int m0 = blockIdx.x * 32;
    const int batch = m0 >> 9;
    const int t = threadIdx.x, w = t >> 6, lane = t & 63;
    const int fm = lane & 15, quad = lane >> 4;
    const int msub = (w >> 1) * 16, ntile0 = (w & 1) * 2;
    const int mrow = m0 + msub + fm;
    f4v acc[2];
    acc[0] = (f4v){0.f, 0.f, 0.f, 0.f}; acc[1] = acc[0];
    for (int k0 = 0; k0 < H_; k0 += 32) {
        const float* ap = &c[(size_t)mrow * H_ + k0 + quad * 8];
        const float4 a0 = *(const float4*)ap, a1 = *(const float4*)(ap + 4);
        const float xs[8] = {a0.x, a0.y, a0.z, a0.w, a1.x, a1.y, a1.z, a1.w};
        s8v fah, fal;
#pragma unroll
        for (int j = 0; j < 8; ++j) { unsigned short h, l; split2(xs[j], h, l); fah[j] = (short)h; fal[j] = (short)l; }
#pragma unroll
        for (int i = 0; i < 2; ++i) {
            const int tn = ntile0 + i;
            const size_t bo = (size_t)(batch * QL_ + tn * 16 + fm) * H_ + k0 + quad * 8;
            const s8v bh = *(const s8v*)&uh[bo];
            const s8v bl = *(const s8v*)&ul[bo];
            acc[i] = __builtin_amdgcn_mfma_f32_16x16x32_bf16(fah, bh, acc[i], 0, 0, 0);
            acc[i] = __builtin_amdgcn_mfma_f32_16x16x32_bf16(fah, bl, acc[i], 0, 0, 0);
            acc[i] = __builtin_amdgcn_mfma_f32_16x16x32_bf16(fal, bh, acc[i], 0, 0, 0);
        }
    }
#pragma unroll
    for (int i = 0; i < 2; ++i) {
        const int col = (ntile0 + i) * 16 + fm;
        const float bb = beta[batch * QL_ + col];
#pragma unroll
        for (int r = 0; r < 4; ++r) {
            const int lr = msub + quad * 4 + r;
            const float v = acc[i][r] + bb;
            s[(size_t)(m0 + lr) * QL_ + col] = v;   // raw s for column softmax pass
            sL[lr][col] = v;
        }
    }
    __syncthreads();
    // row softmax over q dim (64 cols), 8 rows per wave
    const bool qm = q_mask[batch * QL_ + lane] != 0;
#pragma unroll
    for (int rr = 0; rr < 8; ++rr) {
        const int lr = w * 8 + rr;
        const float x = qm ? sL[lr][lane] : -1e30f;
        float mx = x;
#pragma unroll
        for (int o = 32; o; o >>= 1) mx = fmaxf(mx, __shfl_xor(mx, o));
        const float e = __expf(x - mx);
        float sm = e;
#pragma unroll
        for (int o = 32; o; o >>= 1) sm += __shfl_xor(sm, o);
        s1[(size_t)(m0 + lr) * QL_ + lane] = bf16_rne(e / sm);
    }
}

// ---------- K3: s2^T = col softmax (c dim), transposed -> bf16 [b][q][c] ----------
__global__ __launch_bounds__(256) void k_sm_cols(const float* __restrict__ s,
    const int* __restrict__ c_mask, unsigned short* __restrict__ s2t)
{
    __shared__ float red[4];
    const int b = blockIdx.x >> 6, qi = blockIdx.x & 63;
    const int t = threadIdx.x;
    const float* sb = s + (size_t)b * CL_ * QL_ + qi;
    const int* cm = c_mask + b * CL_;
    float x0 = cm[t] ? sb[(size_t)t * QL_] : -1e30f;
    float x1 = cm[t + 256] ? sb[(size_t)(t + 256) * QL_] : -1e30f;
    float m = fmaxf(x0, x1);
#pragma unroll
    for (int o = 32; o; o >>= 1) m = fmaxf(m, __shfl_xor(m, o));
    if ((t & 63) == 0) red[t >> 6] = m;
    __syncthreads();
    m = fmaxf(fmaxf(red[0], red[1]), fmaxf(red[2], red[3]));
    __syncthreads();
    float e0 = __expf(x0 - m), e1 = __expf(x1 - m);
    float sm = e0 + e1;
#pragma unroll
    for (int o = 32; o; o >>= 1) sm += __shfl_xor(sm, o);
    if ((t & 63) == 0) red[t >> 6] = sm;
    __syncthreads();
    sm = red[0] + red[1] + red[2] + red[3];
    float inv = 1.f / sm;
    unsigned short* o = s2t + ((size_t)b * QL_ + qi) * CL_;
    o[t]       = bf16_rne(e0 * inv);
    o[t + 256] = bf16_rne(e1 * inv);
}

// ---------- K4: fused t + finalize.
//   phase 0: stage qT[h][q] (bf16, LDS) for this h-slice
//   phase 1: tT[h][q] = (s2^T @ c) for this h-slice (MFMA, c transposed via LDS)
//   phase 2: a = s1@q, bvec = s1@t; out = [c, a, c*a, c*bvec] ----------
__global__ __launch_bounds__(256) void k_tfin(const unsigned short* __restrict__ s2t,
    const unsigned short* __restrict__ s1, const float* __restrict__ q,
    const float* __restrict__ c, float* __restrict__ out)
{
    __shared__ unsigned short Bs[64][40];   // c^T staging tile (h x d)
    __shared__ unsigned short qT[64][72];   // q^T bf16 (h x q)
    __shared__ unsigned short tT[64][72];   // t    bf16 (h x q)
    const int h0 = blockIdx.x * 64;
    const int c0 = blockIdx.y * 256;
    const int b  = blockIdx.z;
    const int t = threadIdx.x, w = t >> 6, lane = t & 63;
    const int fm = lane & 15, quad = lane >> 4;

    // ---- phase 0: stage q^T ----
    {
        const int r = t >> 4, c4 = (t & 15) * 4;
#pragma unroll
        for (int i = 0; i < 4; ++i) {
            const int qr = r + 16 * i;
            const float4 v = *(const float4*)&q[((size_t)b * QL_ + qr) * H_ + h0 + c4];
            qT[c4 + 0][qr] = bf16_rne(v.x);
            qT[c4 + 1][qr] = bf16_rne(v.y);
            qT[c4 + 2][qr] = bf16_rne(v.z);
            qT[c4 + 3][qr] = bf16_rne(v.w);
        }
    }

    // ---- phase 1: tT = (s2^T @ c) h-slice ----
    {
        const int dd = t >> 3, hc = (t & 7) * 8;
        f4v acc[4];
#pragma unroll
        for (int j = 0; j < 4; ++j) acc[j] = (f4v){0.f, 0.f, 0.f, 0.f};
        for (int d0 = 0; d0 < CL_; d0 += 32) {
            const float* cp = &c[((size_t)b * CL_ + d0 + dd) * H_ + h0 + hc];
            const float4 v0 = *(const float4*)cp, v1 = *(const float4*)(cp + 4);
            const float xs[8] = {v0.x, v0.y, v0.z, v0.w, v1.x, v1.y, v1.z, v1.w};
            __syncthreads();   // also covers phase-0 qT writes on first iteration
#pragma unroll
            for (int j = 0; j < 8; ++j) Bs[hc + j][dd] = bf16_rne(xs[j]);
            __syncthreads();
            const s8v fb = *(const s8v*)&Bs[w * 16 + fm][quad * 8];
#pragma unroll
            for (int tm = 0; tm < 4; ++tm) {
                const s8v fa = *(const s8v*)&s2t[((size_t)b * QL_ + tm * 16 + fm) * CL_ + d0 + quad * 8];
                acc[tm] = __builtin_amdgcn_mfma_f32_16x16x32_bf16(fa, fb, acc[tm], 0, 0, 0);
            }
        }
#pragma unroll
        for (int tm = 0; tm < 4; ++tm)
#pragma unroll
            for (int r = 0; r < 4; ++r)
                tT[w * 16 + fm][tm * 16 + quad * 4 + r] = bf16_rne(acc[tm][r]);
    }
    __syncthreads();

    // ---- phase 2: finalize ----
    const int cbase = c0 + w * 64;
    f4v aa[4][4], bb[4][4];
#pragma unroll
    for (int i = 0; i < 4; ++i)
#pragma unroll
        for (int j = 0; j < 4; ++j) { aa[i][j] = (f4v){0.f, 0.f, 0.f, 0.f}; bb[i][j] = aa[i][j]; }
#pragma unroll
    for (int ks = 0; ks < 2; ++ks) {
        s8v fa[4], fq[4], ft[4];
#pragma unroll
        for (int tm = 0; tm < 4; ++tm)
            fa[tm] = *(const s8v*)&s1[(size_t)(b * CL_ + cbase + tm * 16 + fm) * QL_ + ks * 32 + quad * 8];
#pragma unroll
        for (int tn = 0; tn < 4; ++tn) {
            fq[tn] = *(const s8v*)&qT[tn * 16 + fm][ks * 32 + quad * 8];
            ft[tn] = *(const s8v*)&tT[tn * 16 + fm][ks * 32 + quad * 8];
        }
#pragma unroll
        for (int tm = 0; tm < 4; ++tm)
#pragma unroll
            for (int tn = 0; tn < 4; ++tn) {
                aa[tm][tn] = __builtin_amdgcn_mfma_f32_16x16x32_bf16(fa[tm], fq[tn], aa[tm][tn], 0, 0, 0);
                bb[tm][tn] = __builtin_amdgcn_mfma_f32_16x16x32_bf16(fa[tm], ft[tn], bb[tm][tn], 0, 0, 0);
            }
    }
#pragma unroll
    for (int tm = 0; tm < 4; ++tm)
#pragma unroll
        for (int tn = 0; tn < 4; ++tn) {
            const int h = h0 + tn * 16 + fm;
#pragma unroll
            for (int r = 0; r < 4; ++r) {
                const int crow = cbase + tm * 16 + quad * 4 + r;
                const float cv = c[((size_t)b * CL_ + crow) * H_ + h];
                const float av = aa[tm][tn][r], bv = bb[tm][tn][r];
                float* ob = out + (size_t)(b * CL_ + crow) * (4 * H_);
                ob[h]           = cv;
                ob[H_ + h]      = av;
                ob[2 * H_ + h]  = cv * av;
                ob[3 * H_ + h]  = cv * bv;
            }
        }
}

extern "C" void kernel_launch(void* const* d_in, const int* in_sizes, int n_in,
                              void* d_out, int out_size, void* d_ws, size_t ws_size,
                              hipStream_t stream) {
    const float* c      = (const float*)d_in[0];
    const float* q      = (const float*)d_in[1];
    const int*   c_mask = (const int*)d_in[2];
    const int*   q_mask = (const int*)d_in[3];
    const float* W      = (const float*)d_in[4];
    const float* bias   = (const float*)d_in[5];
    float* out = (float*)d_out;

    // workspace (bytes, 16B-aligned), total ~7.3 MB
    char* base = (char*)d_ws;
    unsigned short* uh   = (unsigned short*)(base);              // 1572864
    unsigned short* ul   = (unsigned short*)(base + 1572864);    // 1572864
    float*          beta = (float*)(base + 3145728);             // 4096
    float*          s    = (float*)(base + 3149824);             // 2097152
    unsigned short* s1   = (unsigned short*)(base + 5246976);    // 1048576
    unsigned short* s2t  = (unsigned short*)(base + 6295552);    // 1048576

    dim3 blk(256);
    k_u_beta <<<dim3(192 + 256),  blk, 0, stream>>>(q, W, bias, uh, ul, beta);
    k_s_sm   <<<dim3(256),        blk, 0, stream>>>(c, uh, ul, beta, q_mask, s, s1);
    k_sm_cols<<<dim3(B_ * QL_),   blk, 0, stream>>>(s, c_mask, s2t);
    k_tfin   <<<dim3(12, 2, B_),  blk, 0, stream>>>(s2t, s1, q, c, out);
}